// Round 3
// baseline (193.309 us; speedup 1.0000x reference)
//
#include <hip/hip_runtime.h>

#define T_SEQ 4096
#define CDIM 384

typedef __attribute__((ext_vector_type(8))) short short8;
typedef __attribute__((ext_vector_type(4))) short short4e;
typedef __attribute__((ext_vector_type(4))) float float4e;

#define KSCALE 0.05103103630798288f            /* 384^-0.5 */
#define KE (KSCALE * 1.4426950408889634f)      /* scale * log2(e), folded into Q */

__device__ inline unsigned short f2bf(float f) {
  unsigned u = __builtin_bit_cast(unsigned, f);
  u += 0x7FFFu + ((u >> 16) & 1u);             // round-to-nearest-even
  return (unsigned short)(u >> 16);
}

template<int C>
__device__ inline float dppf(float x) {
  return __builtin_bit_cast(float,
      __builtin_amdgcn_update_dpp(0, __builtin_bit_cast(int, x), C, 0xF, 0xF, false));
}
__device__ inline float rmax16(float x) {
  x = fmaxf(x, dppf<0xB1>(x));    // quad_perm xor1
  x = fmaxf(x, dppf<0x4E>(x));    // quad_perm xor2
  x = fmaxf(x, dppf<0x141>(x));   // row_half_mirror
  x = fmaxf(x, dppf<0x140>(x));   // row_mirror
  return x;
}
__device__ inline float rsum16(float x) {
  x += dppf<0xB1>(x);
  x += dppf<0x4E>(x);
  x += dppf<0x141>(x);
  x += dppf<0x140>(x);
  return x;
}

// ---------------- projection: K = x Wk^T + bk ; V(=Q) = x Wv^T + bv ----------
__global__ __launch_bounds__(256) void proj_kernel(
    const float* __restrict__ x, const float* __restrict__ Wk, const float* __restrict__ bk,
    const float* __restrict__ Wv, const float* __restrict__ bv,
    unsigned short* __restrict__ Krow, unsigned short* __restrict__ Qrow,
    unsigned short* __restrict__ Vt) {
  __shared__ alignas(16) unsigned short Wl[128 * 40];
  const int tid = threadIdx.x;
  const int lane = tid & 63;
  const int wv = tid >> 6;
  const int lid = lane & 15, quad = lane >> 4;
  const int rowbase = blockIdx.x * 64 + wv * 16;
  const float* xr = x + (size_t)(rowbase + lid) * CDIM;

  float4e acc[8];
#pragma unroll
  for (int n = 0; n < 8; n++) acc[n] = (float4e){0.f, 0.f, 0.f, 0.f};

  for (int kc = 0; kc < 12; kc++) {
    const int ko = kc * 32;
#pragma unroll
    for (int i = 0; i < 4; i++) {
      const int f = tid + 256 * i;
      const int col = f >> 3, part = f & 7;
      const float* wsrc = (col < 64) ? (Wk + (size_t)col * CDIM + ko + part * 4)
                                     : (Wv + (size_t)(col - 64) * CDIM + ko + part * 4);
      float4e w4 = *(const float4e*)wsrc;
      short4e s;
#pragma unroll
      for (int j = 0; j < 4; j++) s[j] = (short)f2bf(w4[j]);
      *(short4e*)(&Wl[col * 40 + part * 4]) = s;
    }
    __syncthreads();
    float4e a0 = *(const float4e*)(xr + ko + quad * 8);
    float4e a1 = *(const float4e*)(xr + ko + quad * 8 + 4);
    short8 af;
#pragma unroll
    for (int j = 0; j < 4; j++) { af[j] = (short)f2bf(a0[j]); af[4 + j] = (short)f2bf(a1[j]); }
#pragma unroll
    for (int n = 0; n < 8; n++) {
      short8 bf = *(const short8*)(&Wl[(n * 16 + lid) * 40 + quad * 8]);
      acc[n] = __builtin_amdgcn_mfma_f32_16x16x32_bf16(af, bf, acc[n], 0, 0, 0);
    }
    __syncthreads();
  }
  const int rbase = rowbase + quad * 4;
#pragma unroll
  for (int n = 0; n < 8; n++) {
    const int col = n * 16 + lid;
    const float bias = (n < 4) ? bk[col] : bv[col - 64];
#pragma unroll
    for (int i = 0; i < 4; i++) {
      const int row = rbase + i;
      const float val = acc[n][i] + bias;
      if (n < 4) {
        Krow[(size_t)row * 64 + col] = f2bf(val);
      } else {
        const int hh = col - 64;
        Qrow[(size_t)row * 64 + hh] = f2bf(val * KE);   // pre-scaled query
        const int b = row >> 12, t = row & 4095;
        Vt[(size_t)(b * 64 + hh) * T_SEQ + t] = f2bf(val);
      }
    }
  }
}

// ---------------- flash attention: 4 waves/block, no intra-block barriers ----
// Block = (b, qb, seg): wave wv handles q-tile qt = qb*4+wv (32 q-rows),
// K-range [seg*seg_tiles, min(qt+1, seg*seg_tiles+seg_tiles)) in 32-key tiles.
// Valid blocks satisfy seg*seg_tiles <= 4*qb so every wave has work.
__global__ __launch_bounds__(256) void attn_kernel(
    const unsigned short* __restrict__ Krow, const unsigned short* __restrict__ Qrow,
    const unsigned short* __restrict__ Vt,
    float* __restrict__ Opart, float* __restrict__ MLpart,
    int seg_tiles, int maxseg, int segshift) {
  const int j = blockIdx.x;
  const int b = j & 3;
  const int rest = j >> 2;
  const int qb = 31 - (rest >> segshift);    // heavy q-blocks first
  const int seg = rest & (maxseg - 1);
  if (seg * seg_tiles > qb * 4) return;      // uniform: whole block exits

  const int wv = threadIdx.x >> 6;
  const int lane = threadIdx.x & 63;
  const int lid = lane & 15, quad = lane >> 4;
  const int qt = qb * 4 + wv;
  const int q0 = qt * 32;
  const int t0 = seg * seg_tiles;
  const int tend0 = t0 + seg_tiles;
  const int t1 = (qt + 1 < tend0) ? (qt + 1) : tend0;

  const unsigned short* Qb = Qrow + (size_t)(b * T_SEQ + q0) * 64;
  const unsigned short* Kb = Krow + (size_t)(b * T_SEQ) * 64;
  const unsigned short* Vb = Vt + (size_t)(b * 64) * T_SEQ;

  short8 Qf[2][2];
#pragma unroll
  for (int r = 0; r < 2; r++)
#pragma unroll
    for (int h = 0; h < 2; h++)
      Qf[r][h] = *(const short8*)(Qb + (size_t)(r * 16 + lid) * 64 + h * 32 + quad * 8);

  float4e O[2][4];
  float4e mrow[2], lrow[2];
#pragma unroll
  for (int r = 0; r < 2; r++) {
#pragma unroll
    for (int cc = 0; cc < 4; cc++) O[r][cc] = (float4e){0.f, 0.f, 0.f, 0.f};
#pragma unroll
    for (int i = 0; i < 4; i++) { mrow[r][i] = -__builtin_inff(); lrow[r][i] = 0.f; }
  }

  __shared__ alignas(16) unsigned short PbAll[4][2][16 * 40];  // per-wave buffers
  unsigned short (&Pb)[2][16 * 40] = PbAll[wv];
  const float4e zero4 = (float4e){0.f, 0.f, 0.f, 0.f};

  short8 Kc[2][2], Vc[4], Kn[2][2], Vn[4];
  {
    const int k0 = t0 * 32;
#pragma unroll
    for (int c = 0; c < 2; c++)
#pragma unroll
      for (int h = 0; h < 2; h++)
        Kc[c][h] = *(const short8*)(Kb + (size_t)(k0 + c * 16 + lid) * 64 + h * 32 + quad * 8);
#pragma unroll
    for (int cc = 0; cc < 4; cc++)
      Vc[cc] = *(const short8*)(Vb + (size_t)(cc * 16 + lid) * T_SEQ + k0 + quad * 8);
  }

  for (int kt = t0; kt < t1; kt++) {
    const int k0 = kt * 32;
    if (kt + 1 < t1) {     // wave-uniform prefetch of next tile
      const int kn0 = k0 + 32;
#pragma unroll
      for (int c = 0; c < 2; c++)
#pragma unroll
        for (int h = 0; h < 2; h++)
          Kn[c][h] = *(const short8*)(Kb + (size_t)(kn0 + c * 16 + lid) * 64 + h * 32 + quad * 8);
#pragma unroll
      for (int cc = 0; cc < 4; cc++)
        Vn[cc] = *(const short8*)(Vb + (size_t)(cc * 16 + lid) * T_SEQ + kn0 + quad * 8);
    }

    float4e S[2][2];
#pragma unroll
    for (int r = 0; r < 2; r++)
#pragma unroll
      for (int c = 0; c < 2; c++) {
        float4e s = __builtin_amdgcn_mfma_f32_16x16x32_bf16(Qf[r][0], Kc[c][0], zero4, 0, 0, 0);
        S[r][c] = __builtin_amdgcn_mfma_f32_16x16x32_bf16(Qf[r][1], Kc[c][1], s, 0, 0, 0);
      }

#pragma unroll
    for (int r = 0; r < 2; r++) {
      const int wbase = q0 + r * 16;
      if (k0 + 31 > wbase) {   // causal mask (diagonal tiles only)
#pragma unroll
        for (int c = 0; c < 2; c++) {
          const int colv = k0 + c * 16 + lid;
#pragma unroll
          for (int i = 0; i < 4; i++)
            if (colv > wbase + quad * 4 + i) S[r][c][i] = -__builtin_inff();
        }
      }
      float4e al, P0, P1;
#pragma unroll
      for (int i = 0; i < 4; i++) {
        const float tm = rmax16(fmaxf(S[r][0][i], S[r][1][i]));
        const float mn = fmaxf(mrow[r][i], tm);
        al[i] = __builtin_amdgcn_exp2f(mrow[r][i] - mn);
        P0[i] = __builtin_amdgcn_exp2f(S[r][0][i] - mn);
        P1[i] = __builtin_amdgcn_exp2f(S[r][1][i] - mn);
        const float rs = rsum16(P0[i] + P1[i]);
        lrow[r][i] = lrow[r][i] * al[i] + rs;
        mrow[r][i] = mn;
        Pb[r][(quad * 4 + i) * 40 + lid]      = f2bf(P0[i]);
        Pb[r][(quad * 4 + i) * 40 + 16 + lid] = f2bf(P1[i]);
      }
#pragma unroll
      for (int cc = 0; cc < 4; cc++)
#pragma unroll
        for (int i = 0; i < 4; i++) O[r][cc][i] *= al[i];
    }
    // per-wave LDS write->read ordering (no __syncthreads: waves independent)
    __builtin_amdgcn_wave_barrier();
    __asm__ __volatile__("s_waitcnt lgkmcnt(0)" ::: "memory");
    const short8 Pf0 = *(const short8*)(&Pb[0][lid * 40 + quad * 8]);
    const short8 Pf1 = *(const short8*)(&Pb[1][lid * 40 + quad * 8]);
#pragma unroll
    for (int cc = 0; cc < 4; cc++) {
      O[0][cc] = __builtin_amdgcn_mfma_f32_16x16x32_bf16(Pf0, Vc[cc], O[0][cc], 0, 0, 0);
      O[1][cc] = __builtin_amdgcn_mfma_f32_16x16x32_bf16(Pf1, Vc[cc], O[1][cc], 0, 0, 0);
    }
    __builtin_amdgcn_wave_barrier();   // keep next-iter P writes after Pf reads
#pragma unroll
    for (int c = 0; c < 2; c++)
#pragma unroll
      for (int h = 0; h < 2; h++) Kc[c][h] = Kn[c][h];
#pragma unroll
    for (int cc = 0; cc < 4; cc++) Vc[cc] = Vn[cc];
  }

  // write partial (unnormalized O, m, l) — m/l in log2-scaled domain
  const size_t pidx = (size_t)(b * 128 + qt) * maxseg + seg;
  float* Ob = Opart + pidx * 2048;
#pragma unroll
  for (int r = 0; r < 2; r++)
#pragma unroll
    for (int cc = 0; cc < 4; cc++)
#pragma unroll
      for (int i = 0; i < 4; i++)
        Ob[(size_t)(r * 16 + quad * 4 + i) * 64 + cc * 16 + lid] = O[r][cc][i];
  float* ml = MLpart + pidx * 64;
  if (lid == 0) {
#pragma unroll
    for (int r = 0; r < 2; r++)
#pragma unroll
      for (int i = 0; i < 4; i++) {
        ml[r * 16 + quad * 4 + i]      = mrow[r][i];
        ml[32 + r * 16 + quad * 4 + i] = lrow[r][i];
      }
  }
}

// ---------------- combine split-K partials and normalize ---------------------
__global__ __launch_bounds__(256) void combine_kernel(
    const float* __restrict__ Opart, const float* __restrict__ MLpart,
    float* __restrict__ out, int segtileshift, int maxseg) {
  const int bq = blockIdx.x;          // b*128 + qt
  const int qt = bq & 127;
  const int nseg = (qt >> segtileshift) + 1;
  const int tid = threadIdx.x;
  __shared__ float sW[8][32], sDen[32];
  const float* ml = MLpart + (size_t)bq * maxseg * 64;
  if (tid < 32) {
    float M = ml[tid];
    for (int s = 1; s < nseg; s++) M = fmaxf(M, ml[s * 64 + tid]);
    float den = 0.f;
    for (int s = 0; s < nseg; s++) {
      const float w = __builtin_amdgcn_exp2f(ml[s * 64 + tid] - M);  // log2 domain
      sW[s][tid] = w;
      den += w * ml[s * 64 + 32 + tid];
    }
    sDen[tid] = den;
  }
  __syncthreads();
  const float* Ob = Opart + (size_t)bq * maxseg * 2048;
  float* ob = out + (size_t)bq * 2048;
#pragma unroll
  for (int e = tid; e < 2048; e += 256) {
    const int r = e >> 6;
    float acc = 0.f;
    for (int s = 0; s < nseg; s++) acc += sW[s][r] * Ob[s * 2048 + e];
    ob[e] = acc / sDen[r];
  }
}

extern "C" void kernel_launch(void* const* d_in, const int* in_sizes, int n_in,
                              void* d_out, int out_size, void* d_ws, size_t ws_size,
                              hipStream_t stream) {
  const float* x  = (const float*)d_in[0];
  const float* Wk = (const float*)d_in[1];
  const float* bk = (const float*)d_in[2];
  // d_in[3]=Wq, d_in[4]=bq unused (reference bug: q uses value projection)
  const float* Wv = (const float*)d_in[5];
  const float* bv = (const float*)d_in[6];
  float* out = (float*)d_out;
  char* ws = (char*)d_ws;

  unsigned short* Krow = (unsigned short*)(ws);                   // 2 MB
  unsigned short* Qrow = (unsigned short*)(ws + (2u << 20));      // 2 MB
  unsigned short* Vt   = (unsigned short*)(ws + (4u << 20));      // 2 MB
  float* Opart = (float*)(ws + (6u << 20));

  int maxseg, segshift, sts, seg_tiles;
  if (ws_size >= ((size_t)40 << 20))      { maxseg = 8; segshift = 3; sts = 4; seg_tiles = 16; }
  else if (ws_size >= ((size_t)24 << 20)) { maxseg = 4; segshift = 2; sts = 5; seg_tiles = 32; }
  else                                    { maxseg = 1; segshift = 0; sts = 7; seg_tiles = 128; }
  float* MLpart = (float*)(ws + (6u << 20) + (size_t)maxseg * 512 * 2048 * 4);

  hipLaunchKernelGGL(proj_kernel, dim3(256), dim3(256), 0, stream,
                     x, Wk, bk, Wv, bv, Krow, Qrow, Vt);
  hipLaunchKernelGGL(attn_kernel, dim3(4 * 32 * maxseg), dim3(256), 0, stream,
                     Krow, Qrow, Vt, Opart, MLpart, seg_tiles, maxseg, segshift);
  hipLaunchKernelGGL(combine_kernel, dim3(512), dim3(256), 0, stream,
                     Opart, MLpart, out, sts, maxseg);
}

// Round 4
// 169.281 us; speedup vs baseline: 1.1419x; 1.1419x over previous
//
#include <hip/hip_runtime.h>

#define T_SEQ 4096
#define CDIM 384

typedef __attribute__((ext_vector_type(8))) short short8;
typedef __attribute__((ext_vector_type(4))) short short4e;
typedef __attribute__((ext_vector_type(4))) float float4e;

#define KSCALE 0.05103103630798288f            /* 384^-0.5 */
#define KE (KSCALE * 1.4426950408889634f)      /* scale * log2(e), folded into Q */

__device__ inline unsigned short f2bf(float f) {
  unsigned u = __builtin_bit_cast(unsigned, f);
  u += 0x7FFFu + ((u >> 16) & 1u);             // round-to-nearest-even
  return (unsigned short)(u >> 16);
}

template<int C>
__device__ inline float dppf(float x) {
  return __builtin_bit_cast(float,
      __builtin_amdgcn_update_dpp(0, __builtin_bit_cast(int, x), C, 0xF, 0xF, false));
}
__device__ inline float rmax16(float x) {
  x = fmaxf(x, dppf<0xB1>(x));
  x = fmaxf(x, dppf<0x4E>(x));
  x = fmaxf(x, dppf<0x141>(x));
  x = fmaxf(x, dppf<0x140>(x));
  return x;
}
__device__ inline float rsum16(float x) {
  x += dppf<0xB1>(x);
  x += dppf<0x4E>(x);
  x += dppf<0x141>(x);
  x += dppf<0x140>(x);
  return x;
}

// async 16B/lane global->LDS DMA (lane i lands at ldsbase + i*16)
__device__ inline void dma16(const void* g, void* l) {
  __builtin_amdgcn_global_load_lds(
      (const __attribute__((address_space(1))) unsigned int*)g,
      (__attribute__((address_space(3))) unsigned int*)l, 16, 0, 0);
}

// ---------------- projection -------------------------------------------------
// K = x Wk^T + bk  -> Ktil: 4KB tiles [b][kt][key32][h64], h-granules (16B)
//                    XOR-swizzled by (key&7) for conflict-free LDS frag reads.
// V(=Q) = x Wv^T+bv -> Qrow row-major (pre-scaled by KE); Vtil: 4KB tiles
//                    [b][kt][h64][key32], key-granules XOR-swizzled by (h>>1)&3.
__global__ __launch_bounds__(256) void proj_kernel(
    const float* __restrict__ x, const float* __restrict__ Wk, const float* __restrict__ bk,
    const float* __restrict__ Wv, const float* __restrict__ bv,
    unsigned short* __restrict__ Ktil, unsigned short* __restrict__ Qrow,
    unsigned short* __restrict__ Vtil) {
  __shared__ alignas(16) unsigned short Wl[2][128 * 40];
  const int tid = threadIdx.x;
  const int lane = tid & 63;
  const int wv = tid >> 6;
  const int lid = lane & 15, quad = lane >> 4;
  const int rowbase = blockIdx.x * 64 + wv * 16;
  const float* xr = x + (size_t)(rowbase + lid) * CDIM;

  // W-chunk register staging (prefetch distance 1 chunk)
  float4e wreg[4];
  int wcol[4], wpart[4];
#pragma unroll
  for (int i = 0; i < 4; i++) {
    const int f = tid + 256 * i;
    wcol[i] = f >> 3; wpart[i] = f & 7;
  }
  auto wload = [&](int kc) {
#pragma unroll
    for (int i = 0; i < 4; i++) {
      const float* wsrc = (wcol[i] < 64)
          ? (Wk + (size_t)wcol[i] * CDIM + kc * 32 + wpart[i] * 4)
          : (Wv + (size_t)(wcol[i] - 64) * CDIM + kc * 32 + wpart[i] * 4);
      wreg[i] = *(const float4e*)wsrc;
    }
  };
  auto wstage = [&](int bufi) {
#pragma unroll
    for (int i = 0; i < 4; i++) {
      short4e s;
#pragma unroll
      for (int jj = 0; jj < 4; jj++) s[jj] = (short)f2bf(wreg[i][jj]);
      *(short4e*)(&Wl[bufi][wcol[i] * 40 + wpart[i] * 4]) = s;
    }
  };

  // x prefetch (distance 2 chunks)
  float4e xa0[2], xa1[2];
  auto xload = [&](int kc, int slot) {
    xa0[slot] = *(const float4e*)(xr + kc * 32 + quad * 8);
    xa1[slot] = *(const float4e*)(xr + kc * 32 + quad * 8 + 4);
  };

  wload(0); wstage(0);          // chunk 0 -> buf 0
  wload(1);                     // chunk 1 regs in flight
  xload(0, 0); xload(1, 1);
  __syncthreads();

  float4e acc[8];
#pragma unroll
  for (int n = 0; n < 8; n++) acc[n] = (float4e){0.f, 0.f, 0.f, 0.f};

  for (int kc = 0; kc < 12; kc++) {
    if (kc < 11) wstage((kc + 1) & 1);   // write chunk kc+1 (regs from last iter)
    if (kc < 10) wload(kc + 2);          // issue chunk kc+2 loads
    const int slot = kc & 1;
    short8 af;
#pragma unroll
    for (int jj = 0; jj < 4; jj++) {
      af[jj] = (short)f2bf(xa0[slot][jj]);
      af[4 + jj] = (short)f2bf(xa1[slot][jj]);
    }
    if (kc < 10) xload(kc + 2, slot);    // refill the slot just consumed
#pragma unroll
    for (int n = 0; n < 8; n++) {
      short8 bf = *(const short8*)(&Wl[kc & 1][(n * 16 + lid) * 40 + quad * 8]);
      acc[n] = __builtin_amdgcn_mfma_f32_16x16x32_bf16(af, bf, acc[n], 0, 0, 0);
    }
    __syncthreads();
  }

  // epilogue: D rows = quad*4+i, cols = n*16+lid ; swizzled tile writes
  const int rbase = rowbase + quad * 4;
#pragma unroll
  for (int n = 0; n < 8; n++) {
    const int col = n * 16 + lid;
    const float bias = (n < 4) ? bk[col] : bv[col - 64];
#pragma unroll
    for (int i = 0; i < 4; i++) {
      const int row = rbase + i;
      const float val = acc[n][i] + bias;
      const int b = row >> 12, t = row & 4095;
      const int kt = t >> 5, ko = t & 31;
      const size_t tile = (size_t)(b * 128 + kt) * 2048;
      if (n < 4) {
        // K: [key32][granule(h)^ (key&7)][8h]
        Ktil[tile + ko * 64 + (((col >> 3) ^ (ko & 7)) * 8) + (col & 7)] = f2bf(val);
      } else {
        const int hh = col - 64;
        Qrow[(size_t)row * 64 + hh] = f2bf(val * KE);   // pre-scaled query
        // V^T: [h64][granule(key) ^ ((h>>1)&3)][8key]
        Vtil[tile + hh * 32 + (((ko >> 3) ^ ((hh >> 1) & 3)) * 8) + (ko & 7)] = f2bf(val);
      }
    }
  }
}

// ---------------- flash attention: 1 wave/block, DMA-fed double-buffered LDS -
__global__ __launch_bounds__(64) void attn_kernel(
    const unsigned short* __restrict__ Ktil, const unsigned short* __restrict__ Qrow,
    const unsigned short* __restrict__ Vtil,
    float* __restrict__ Opart, float* __restrict__ MLpart,
    int seg_tiles, int maxseg, int segshift) {
  __shared__ alignas(16) char lds[18944];   // K dbuf 8KB | V dbuf 8KB | P 2.5KB
  const int j = blockIdx.x;
  const int b = j & 3;
  const int rest = j >> 2;
  const int qt = 127 - (rest >> segshift);   // heavy-first
  const int seg = rest & (maxseg - 1);
  if (seg * seg_tiles > qt) return;

  const int lane = threadIdx.x & 63;
  const int lid = lane & 15, quad = lane >> 4;
  const int q0 = qt * 32;
  const int t0 = seg * seg_tiles;
  const int tend0 = t0 + seg_tiles;
  const int t1 = (qt + 1 < tend0) ? (qt + 1) : tend0;

  const unsigned short* Qb = Qrow + (size_t)(b * T_SEQ + q0) * 64;
  const char* Kg = (const char*)(Ktil + (size_t)(b * 128) * 2048);
  const char* Vg = (const char*)(Vtil + (size_t)(b * 128) * 2048);
  unsigned short* Pb = (unsigned short*)(lds + 16384);

  short8 Qf[2][2];
#pragma unroll
  for (int r = 0; r < 2; r++)
#pragma unroll
    for (int h = 0; h < 2; h++)
      Qf[r][h] = *(const short8*)(Qb + (size_t)(r * 16 + lid) * 64 + h * 32 + quad * 8);

  float4e O[2][4];
  float4e mrow[2], lrow[2];
#pragma unroll
  for (int r = 0; r < 2; r++) {
#pragma unroll
    for (int cc = 0; cc < 4; cc++) O[r][cc] = (float4e){0.f, 0.f, 0.f, 0.f};
#pragma unroll
    for (int i = 0; i < 4; i++) { mrow[r][i] = -__builtin_inff(); lrow[r][i] = 0.f; }
  }
  const float4e zero4 = (float4e){0.f, 0.f, 0.f, 0.f};

  auto issue_tile = [&](int kt, int bufi) {
    const char* kg = Kg + (size_t)kt * 4096;
    const char* vg = Vg + (size_t)kt * 4096;
#pragma unroll
    for (int jj = 0; jj < 4; jj++)
      dma16(kg + jj * 1024 + lane * 16, lds + bufi * 4096 + jj * 1024);
#pragma unroll
    for (int jj = 0; jj < 4; jj++)
      dma16(vg + jj * 1024 + lane * 16, lds + 8192 + bufi * 4096 + jj * 1024);
  };

  issue_tile(t0, 0);

  for (int kt = t0; kt < t1; kt++) {
    const int cb = (kt - t0) & 1, nb = cb ^ 1;
    const int ktn = (kt + 1 < t1) ? kt + 1 : kt;
    issue_tile(ktn, nb);                              // prefetch next tile
    __asm__ __volatile__("s_waitcnt vmcnt(8)" ::: "memory");  // current tile ready

    // K fragments from LDS (swizzled, conflict-free)
    short8 Kf[2][2];
#pragma unroll
    for (int c = 0; c < 2; c++) {
      const int row = c * 16 + lid;
#pragma unroll
      for (int h = 0; h < 2; h++) {
        const int gran = (h * 4 + quad) ^ (row & 7);
        Kf[c][h] = *(const short8*)(lds + cb * 4096 + row * 128 + gran * 16);
      }
    }
    float4e S[2][2];
#pragma unroll
    for (int r = 0; r < 2; r++)
#pragma unroll
      for (int c = 0; c < 2; c++) {
        float4e s = __builtin_amdgcn_mfma_f32_16x16x32_bf16(Qf[r][0], Kf[c][0], zero4, 0, 0, 0);
        S[r][c] = __builtin_amdgcn_mfma_f32_16x16x32_bf16(Qf[r][1], Kf[c][1], s, 0, 0, 0);
      }

    // V fragments from LDS
    short8 Vf[4];
#pragma unroll
    for (int cc = 0; cc < 4; cc++) {
      const int hh = cc * 16 + lid;
      const int gran = quad ^ ((hh >> 1) & 3);
      Vf[cc] = *(const short8*)(lds + 8192 + cb * 4096 + hh * 64 + gran * 16);
    }

    const int k0 = kt * 32;
#pragma unroll
    for (int r = 0; r < 2; r++) {
      const int wbase = q0 + r * 16;
      if (k0 + 31 > wbase) {   // causal mask (diagonal tiles only)
#pragma unroll
        for (int c = 0; c < 2; c++) {
          const int colv = k0 + c * 16 + lid;
#pragma unroll
          for (int i = 0; i < 4; i++)
            if (colv > wbase + quad * 4 + i) S[r][c][i] = -__builtin_inff();
        }
      }
      float4e al, P0, P1;
#pragma unroll
      for (int i = 0; i < 4; i++) {
        const float tm = rmax16(fmaxf(S[r][0][i], S[r][1][i]));
        const float mn = fmaxf(mrow[r][i], tm);
        al[i] = __builtin_amdgcn_exp2f(mrow[r][i] - mn);
        P0[i] = __builtin_amdgcn_exp2f(S[r][0][i] - mn);
        P1[i] = __builtin_amdgcn_exp2f(S[r][1][i] - mn);
        const float rs = rsum16(P0[i] + P1[i]);
        lrow[r][i] = lrow[r][i] * al[i] + rs;
        mrow[r][i] = mn;
        Pb[r * 640 + (quad * 4 + i) * 40 + lid]      = f2bf(P0[i]);
        Pb[r * 640 + (quad * 4 + i) * 40 + 16 + lid] = f2bf(P1[i]);
      }
#pragma unroll
      for (int cc = 0; cc < 4; cc++)
#pragma unroll
        for (int i = 0; i < 4; i++) O[r][cc][i] *= al[i];
    }
    // per-wave LDS write->read ordering (single-wave block)
    __builtin_amdgcn_wave_barrier();
    __asm__ __volatile__("s_waitcnt lgkmcnt(0)" ::: "memory");
    const short8 Pf0 = *(const short8*)(&Pb[lid * 40 + quad * 8]);
    const short8 Pf1 = *(const short8*)(&Pb[640 + lid * 40 + quad * 8]);
#pragma unroll
    for (int cc = 0; cc < 4; cc++) {
      O[0][cc] = __builtin_amdgcn_mfma_f32_16x16x32_bf16(Pf0, Vf[cc], O[0][cc], 0, 0, 0);
      O[1][cc] = __builtin_amdgcn_mfma_f32_16x16x32_bf16(Pf1, Vf[cc], O[1][cc], 0, 0, 0);
    }
    __builtin_amdgcn_wave_barrier();   // next-iter P writes stay after Pf reads
  }

  // write partial (unnormalized O, m, l) — m/l in log2-scaled domain
  const size_t pidx = (size_t)(b * 128 + qt) * maxseg + seg;
  float* Ob = Opart + pidx * 2048;
#pragma unroll
  for (int r = 0; r < 2; r++)
#pragma unroll
    for (int cc = 0; cc < 4; cc++)
#pragma unroll
      for (int i = 0; i < 4; i++)
        Ob[(size_t)(r * 16 + quad * 4 + i) * 64 + cc * 16 + lid] = O[r][cc][i];
  float* ml = MLpart + pidx * 64;
  if (lid == 0) {
#pragma unroll
    for (int r = 0; r < 2; r++)
#pragma unroll
      for (int i = 0; i < 4; i++) {
        ml[r * 16 + quad * 4 + i]      = mrow[r][i];
        ml[32 + r * 16 + quad * 4 + i] = lrow[r][i];
      }
  }
}

// ---------------- combine split-K partials and normalize ---------------------
__global__ __launch_bounds__(256) void combine_kernel(
    const float* __restrict__ Opart, const float* __restrict__ MLpart,
    float* __restrict__ out, int segtileshift, int maxseg) {
  const int bq = blockIdx.x;          // b*128 + qt
  const int qt = bq & 127;
  const int nseg = (qt >> segtileshift) + 1;
  const int tid = threadIdx.x;
  __shared__ float sW[4][32], sDen[32];
  const float* ml = MLpart + (size_t)bq * maxseg * 64;
  if (tid < 32) {
    float M = ml[tid];
    for (int s = 1; s < nseg; s++) M = fmaxf(M, ml[s * 64 + tid]);
    float den = 0.f;
    for (int s = 0; s < nseg; s++) {
      const float w = __builtin_amdgcn_exp2f(ml[s * 64 + tid] - M);  // log2 domain
      sW[s][tid] = w;
      den += w * ml[s * 64 + 32 + tid];
    }
    sDen[tid] = den;
  }
  __syncthreads();
  const float* Ob = Opart + (size_t)bq * maxseg * 2048;
  float* ob = out + (size_t)bq * 2048;
#pragma unroll
  for (int e = tid; e < 2048; e += 256) {
    const int r = e >> 6;
    float acc = 0.f;
    for (int s = 0; s < nseg; s++) acc += sW[s][r] * Ob[s * 2048 + e];
    ob[e] = acc / sDen[r];
  }
}

extern "C" void kernel_launch(void* const* d_in, const int* in_sizes, int n_in,
                              void* d_out, int out_size, void* d_ws, size_t ws_size,
                              hipStream_t stream) {
  const float* x  = (const float*)d_in[0];
  const float* Wk = (const float*)d_in[1];
  const float* bk = (const float*)d_in[2];
  // d_in[3]=Wq, d_in[4]=bq unused (reference bug: q uses value projection)
  const float* Wv = (const float*)d_in[5];
  const float* bv = (const float*)d_in[6];
  float* out = (float*)d_out;
  char* ws = (char*)d_ws;

  unsigned short* Ktil = (unsigned short*)(ws);                   // 2 MB
  unsigned short* Qrow = (unsigned short*)(ws + (2u << 20));      // 2 MB
  unsigned short* Vtil = (unsigned short*)(ws + (4u << 20));      // 2 MB
  float* Opart = (float*)(ws + (6u << 20));

  int maxseg, segshift, sts, seg_tiles;
  if (ws_size >= ((size_t)24 << 20)) { maxseg = 4; segshift = 2; sts = 5; seg_tiles = 32; }
  else                               { maxseg = 1; segshift = 0; sts = 7; seg_tiles = 128; }
  float* MLpart = (float*)(ws + (6u << 20) + (size_t)maxseg * 512 * 2048 * 4);

  hipLaunchKernelGGL(proj_kernel, dim3(256), dim3(256), 0, stream,
                     x, Wk, bk, Wv, bv, Ktil, Qrow, Vtil);
  hipLaunchKernelGGL(attn_kernel, dim3(4 * 128 * maxseg), dim3(64), 0, stream,
                     Ktil, Qrow, Vtil, Opart, MLpart, seg_tiles, maxseg, segshift);
  hipLaunchKernelGGL(combine_kernel, dim3(512), dim3(256), 0, stream,
                     Opart, MLpart, out, sts, maxseg);
}

// Round 5
// 151.514 us; speedup vs baseline: 1.2759x; 1.1173x over previous
//
#include <hip/hip_runtime.h>

#define T_SEQ 4096
#define CDIM 384

typedef __attribute__((ext_vector_type(8))) short short8;
typedef __attribute__((ext_vector_type(4))) short short4e;
typedef __attribute__((ext_vector_type(4))) float float4e;

#define KSCALE 0.05103103630798288f            /* 384^-0.5 */
#define KE (KSCALE * 1.4426950408889634f)      /* scale * log2(e), folded into Q */

__device__ inline unsigned short f2bf(float f) {
  unsigned u = __builtin_bit_cast(unsigned, f);
  u += 0x7FFFu + ((u >> 16) & 1u);             // round-to-nearest-even
  return (unsigned short)(u >> 16);
}

// async 16B/lane global->LDS DMA (lane i lands at ldsbase + i*16)
__device__ inline void dma16(const void* g, void* l) {
  __builtin_amdgcn_global_load_lds(
      (const __attribute__((address_space(1))) unsigned int*)g,
      (__attribute__((address_space(3))) unsigned int*)l, 16, 0, 0);
}

// ---------------- projection -------------------------------------------------
// K = x Wk^T + bk  -> Ktil: 4KB tiles [b][kt][key32][h64], 16B h-granules
//                    XOR-swizzled by (key&7) for conflict-free LDS frag reads.
// V(=Q) = x Wv^T+bv -> Qrow row-major (pre-scaled by KE); Vtil: 4KB tiles
//                    [b][kt][h64][key32], key-granules XOR-swizzled by (h>>1)&3.
__global__ __launch_bounds__(128) void proj_kernel(
    const float* __restrict__ x, const float* __restrict__ Wk, const float* __restrict__ bk,
    const float* __restrict__ Wv, const float* __restrict__ bv,
    unsigned short* __restrict__ Ktil, unsigned short* __restrict__ Qrow,
    unsigned short* __restrict__ Vtil) {
  __shared__ alignas(16) unsigned short Wl[2][128 * 40];   // 20 KB -> 2+ blocks/CU
  const int tid = threadIdx.x;
  const int lane = tid & 63;
  const int w = tid >> 6;
  const int lid = lane & 15, quad = lane >> 4;
  const int rowbase = blockIdx.x * 32 + w * 16;
  const float* xr = x + (size_t)(rowbase + lid) * CDIM;

  float4e wreg[8];
  int wcol[8], wpart[8];
#pragma unroll
  for (int i = 0; i < 8; i++) {
    const int f = tid + 128 * i;     // 0..1023 float4-groups of the 128x32 chunk
    wcol[i] = f >> 3; wpart[i] = f & 7;
  }
  auto wload = [&](int kc) {
#pragma unroll
    for (int i = 0; i < 8; i++) {
      const float* wsrc = (wcol[i] < 64)
          ? (Wk + (size_t)wcol[i] * CDIM + kc * 32 + wpart[i] * 4)
          : (Wv + (size_t)(wcol[i] - 64) * CDIM + kc * 32 + wpart[i] * 4);
      wreg[i] = *(const float4e*)wsrc;
    }
  };
  auto wstage = [&](int bufi) {
#pragma unroll
    for (int i = 0; i < 8; i++) {
      short4e s;
#pragma unroll
      for (int jj = 0; jj < 4; jj++) s[jj] = (short)f2bf(wreg[i][jj]);
      *(short4e*)(&Wl[bufi][wcol[i] * 40 + wpart[i] * 4]) = s;
    }
  };
  float4e xa0[2], xa1[2];
  auto xload = [&](int kc, int slot) {
    xa0[slot] = *(const float4e*)(xr + kc * 32 + quad * 8);
    xa1[slot] = *(const float4e*)(xr + kc * 32 + quad * 8 + 4);
  };

  wload(0); wstage(0);
  wload(1);
  xload(0, 0); xload(1, 1);
  __syncthreads();

  float4e acc[8];
#pragma unroll
  for (int n = 0; n < 8; n++) acc[n] = (float4e){0.f, 0.f, 0.f, 0.f};

  for (int kc = 0; kc < 12; kc++) {
    if (kc < 11) wstage((kc + 1) & 1);
    if (kc < 10) wload(kc + 2);
    const int slot = kc & 1;
    short8 af;
#pragma unroll
    for (int jj = 0; jj < 4; jj++) {
      af[jj] = (short)f2bf(xa0[slot][jj]);
      af[4 + jj] = (short)f2bf(xa1[slot][jj]);
    }
    if (kc < 10) xload(kc + 2, slot);
#pragma unroll
    for (int n = 0; n < 8; n++) {
      short8 bf = *(const short8*)(&Wl[kc & 1][(n * 16 + lid) * 40 + quad * 8]);
      acc[n] = __builtin_amdgcn_mfma_f32_16x16x32_bf16(af, bf, acc[n], 0, 0, 0);
    }
    __syncthreads();
  }

  const int rbase = rowbase + quad * 4;
#pragma unroll
  for (int n = 0; n < 8; n++) {
    const int col = n * 16 + lid;
    const float bias = (n < 4) ? bk[col] : bv[col - 64];
#pragma unroll
    for (int i = 0; i < 4; i++) {
      const int row = rbase + i;
      const float val = acc[n][i] + bias;
      const int b = row >> 12, t = row & 4095;
      const int kt = t >> 5, ko = t & 31;
      const size_t tile = (size_t)(b * 128 + kt) * 2048;
      if (n < 4) {
        Ktil[tile + ko * 64 + (((col >> 3) ^ (ko & 7)) * 8) + (col & 7)] = f2bf(val);
      } else {
        const int hh = col - 64;
        Qrow[(size_t)row * 64 + hh] = f2bf(val * KE);   // pre-scaled query
        Vtil[tile + hh * 32 + (((ko >> 3) ^ ((hh >> 1) & 3)) * 8) + (ko & 7)] = f2bf(val);
      }
    }
  }
}

// ---------------- flash attention: S^T = K Q^T, O^T = V^T P ------------------
// C-layout puts q on col=lane&15 -> softmax reduction = in-register + 2 shfl.
__global__ __launch_bounds__(64) void attn_kernel(
    const unsigned short* __restrict__ Ktil, const unsigned short* __restrict__ Qrow,
    const unsigned short* __restrict__ Vtil,
    float* __restrict__ Opart, float* __restrict__ MLpart,
    int seg_tiles, int maxseg, int segshift) {
  __shared__ alignas(16) char lds[18944];   // K dbuf 8K | V dbuf 8K | P^T 2x1280
  const int j = blockIdx.x;
  const int b = j & 3;
  const int rest = j >> 2;
  const int qt = 127 - (rest >> segshift);   // heavy-first
  const int seg = rest & (maxseg - 1);
  if (seg * seg_tiles > qt) return;

  const int lane = threadIdx.x & 63;
  const int lid = lane & 15, quad = lane >> 4;
  const int q0 = qt * 32;
  const int t0 = seg * seg_tiles;
  const int tend0 = t0 + seg_tiles;
  const int t1 = (qt + 1 < tend0) ? (qt + 1) : tend0;

  const unsigned short* Qb = Qrow + (size_t)(b * T_SEQ + q0) * 64;
  const char* Kg = (const char*)(Ktil + (size_t)(b * 128) * 2048);
  const char* Vg = (const char*)(Vtil + (size_t)(b * 128) * 2048);
  unsigned short* PT = (unsigned short*)(lds + 16384);   // [qb][16 q][40 shorts]

  // Q fragments as B-operand: n = q = lid, k = h = quad*8+j
  short8 Qf[2][2];
#pragma unroll
  for (int qb = 0; qb < 2; qb++)
#pragma unroll
    for (int h = 0; h < 2; h++)
      Qf[qb][h] = *(const short8*)(Qb + (size_t)(qb * 16 + lid) * 64 + h * 32 + quad * 8);

  float4e Ot[2][4];          // O^T: row h=quad*4+i (per cc), col q=lid (per qb)
  float mrow[2], lrow[2];    // per-lane q = lid (per qb)
#pragma unroll
  for (int qb = 0; qb < 2; qb++) {
#pragma unroll
    for (int cc = 0; cc < 4; cc++) Ot[qb][cc] = (float4e){0.f, 0.f, 0.f, 0.f};
    mrow[qb] = -__builtin_inff(); lrow[qb] = 0.f;
  }
  const float4e zero4 = (float4e){0.f, 0.f, 0.f, 0.f};

  auto issue_tile = [&](int kt, int bufi) {
    const char* kg = Kg + (size_t)kt * 4096;
    const char* vg = Vg + (size_t)kt * 4096;
#pragma unroll
    for (int jj = 0; jj < 4; jj++)
      dma16(kg + jj * 1024 + lane * 16, lds + bufi * 4096 + jj * 1024);
#pragma unroll
    for (int jj = 0; jj < 4; jj++)
      dma16(vg + jj * 1024 + lane * 16, lds + 8192 + bufi * 4096 + jj * 1024);
  };

  issue_tile(t0, 0);

  for (int kt = t0; kt < t1; kt++) {
    const int cb = (kt - t0) & 1, nb = cb ^ 1;
    const int ktn = (kt + 1 < t1) ? kt + 1 : kt;
    issue_tile(ktn, nb);
    __asm__ __volatile__("s_waitcnt vmcnt(8)" ::: "memory");  // current tile ready

    // K fragments as A-operand: m = key = lid (per kb), k = h = quad*8+j
    short8 Kf[2][2];
#pragma unroll
    for (int kb = 0; kb < 2; kb++) {
      const int row = kb * 16 + lid;
#pragma unroll
      for (int h = 0; h < 2; h++) {
        const int gran = (h * 4 + quad) ^ (row & 7);
        Kf[kb][h] = *(const short8*)(lds + cb * 4096 + row * 128 + gran * 16);
      }
    }
    // V^T fragments as A-operand: m = h = lid (per cc), k = key = quad*8+j
    short8 Vf[4];
#pragma unroll
    for (int cc = 0; cc < 4; cc++) {
      const int hh = cc * 16 + lid;
      const int gran = quad ^ ((hh >> 1) & 3);
      Vf[cc] = *(const short8*)(lds + 8192 + cb * 4096 + hh * 64 + gran * 16);
    }

    // S^T[key][q]: rows = keys (quad*4+i per kb), cols = q (lid)
    float4e St[2][2];
#pragma unroll
    for (int qb = 0; qb < 2; qb++)
#pragma unroll
      for (int kb = 0; kb < 2; kb++) {
        float4e s = __builtin_amdgcn_mfma_f32_16x16x32_bf16(Kf[kb][0], Qf[qb][0], zero4, 0, 0, 0);
        St[qb][kb] = __builtin_amdgcn_mfma_f32_16x16x32_bf16(Kf[kb][1], Qf[qb][1], s, 0, 0, 0);
      }

    const int k0 = kt * 32;
#pragma unroll
    for (int qb = 0; qb < 2; qb++) {
      const int qg = q0 + qb * 16 + lid;
      if (k0 + 31 > q0 + qb * 16) {     // causal mask (diagonal tiles only)
#pragma unroll
        for (int kb = 0; kb < 2; kb++) {
          const int kbase = k0 + kb * 16 + quad * 4;
#pragma unroll
          for (int i = 0; i < 4; i++)
            if (kbase + i > qg) St[qb][kb][i] = -__builtin_inff();
        }
      }
      // softmax over 32 keys for q = lid: in-register + 2 shuffles
      float mx = fmaxf(fmaxf(fmaxf(St[qb][0][0], St[qb][0][1]), fmaxf(St[qb][0][2], St[qb][0][3])),
                       fmaxf(fmaxf(St[qb][1][0], St[qb][1][1]), fmaxf(St[qb][1][2], St[qb][1][3])));
      mx = fmaxf(mx, __shfl_xor(mx, 16));
      mx = fmaxf(mx, __shfl_xor(mx, 32));
      const float mn = fmaxf(mrow[qb], mx);
      const float al = __builtin_amdgcn_exp2f(mrow[qb] - mn);
      float p[2][4], ss = 0.f;
#pragma unroll
      for (int kb = 0; kb < 2; kb++)
#pragma unroll
        for (int i = 0; i < 4; i++) {
          p[kb][i] = __builtin_amdgcn_exp2f(St[qb][kb][i] - mn);
          ss += p[kb][i];
        }
      ss += __shfl_xor(ss, 16);
      ss += __shfl_xor(ss, 32);
      lrow[qb] = lrow[qb] * al + ss;
      mrow[qb] = mn;
      // P^T -> LDS in B-operand layout: [q=lid][key], padded stride 40 shorts
#pragma unroll
      for (int kb = 0; kb < 2; kb++) {
        unsigned d0 = (unsigned)f2bf(p[kb][0]) | ((unsigned)f2bf(p[kb][1]) << 16);
        unsigned d1 = (unsigned)f2bf(p[kb][2]) | ((unsigned)f2bf(p[kb][3]) << 16);
        uint2 dd = {d0, d1};
        *(uint2*)(&PT[qb * 640 + lid * 40 + kb * 16 + quad * 4]) = dd;
      }
#pragma unroll
      for (int cc = 0; cc < 4; cc++)
#pragma unroll
        for (int i = 0; i < 4; i++) Ot[qb][cc][i] *= al;
    }
    // per-wave LDS write->read ordering (single-wave block)
    __builtin_amdgcn_wave_barrier();
    __asm__ __volatile__("s_waitcnt lgkmcnt(0)" ::: "memory");
    short8 Pf[2];
#pragma unroll
    for (int qb = 0; qb < 2; qb++)
      Pf[qb] = *(const short8*)(&PT[qb * 640 + lid * 40 + quad * 8]);
#pragma unroll
    for (int qb = 0; qb < 2; qb++)
#pragma unroll
      for (int cc = 0; cc < 4; cc++)
        Ot[qb][cc] = __builtin_amdgcn_mfma_f32_16x16x32_bf16(Vf[cc], Pf[qb], Ot[qb][cc], 0, 0, 0);
    __builtin_amdgcn_wave_barrier();   // next-iter P writes stay after Pf reads
  }

  // write partial (unnormalized O, m, l) — m/l in log2-scaled domain
  const size_t pidx = (size_t)(b * 128 + qt) * maxseg + seg;
  float* Ob = Opart + pidx * 2048;
#pragma unroll
  for (int qb = 0; qb < 2; qb++)
#pragma unroll
    for (int cc = 0; cc < 4; cc++)
      *(float4e*)(Ob + (size_t)(qb * 16 + lid) * 64 + cc * 16 + quad * 4) = Ot[qb][cc];
  float* ml = MLpart + pidx * 64;
  if (quad == 0) {
#pragma unroll
    for (int qb = 0; qb < 2; qb++) {
      ml[qb * 16 + lid]      = mrow[qb];
      ml[32 + qb * 16 + lid] = lrow[qb];
    }
  }
}

// ---------------- combine split-K partials and normalize ---------------------
__global__ __launch_bounds__(256) void combine_kernel(
    const float* __restrict__ Opart, const float* __restrict__ MLpart,
    float* __restrict__ out, int segtileshift, int maxseg) {
  const int bq = blockIdx.x;          // b*128 + qt
  const int qt = bq & 127;
  const int nseg = (qt >> segtileshift) + 1;
  const int tid = threadIdx.x;
  __shared__ float sW[4][32], sDen[32];
  const float* ml = MLpart + (size_t)bq * maxseg * 64;
  if (tid < 32) {
    float M = ml[tid];
    for (int s = 1; s < nseg; s++) M = fmaxf(M, ml[s * 64 + tid]);
    float den = 0.f;
    for (int s = 0; s < nseg; s++) {
      const float w = __builtin_amdgcn_exp2f(ml[s * 64 + tid] - M);  // log2 domain
      sW[s][tid] = w;
      den += w * ml[s * 64 + 32 + tid];
    }
    sDen[tid] = den;
  }
  __syncthreads();
  const float* Ob = Opart + (size_t)bq * maxseg * 2048;
  float* ob = out + (size_t)bq * 2048;
#pragma unroll
  for (int e = tid; e < 2048; e += 256) {
    const int r = e >> 6;
    float acc = 0.f;
    for (int s = 0; s < nseg; s++) acc += sW[s][r] * Ob[s * 2048 + e];
    ob[e] = acc / sDen[r];
  }
}

extern "C" void kernel_launch(void* const* d_in, const int* in_sizes, int n_in,
                              void* d_out, int out_size, void* d_ws, size_t ws_size,
                              hipStream_t stream) {
  const float* x  = (const float*)d_in[0];
  const float* Wk = (const float*)d_in[1];
  const float* bk = (const float*)d_in[2];
  // d_in[3]=Wq, d_in[4]=bq unused (reference bug: q uses value projection)
  const float* Wv = (const float*)d_in[5];
  const float* bv = (const float*)d_in[6];
  float* out = (float*)d_out;
  char* ws = (char*)d_ws;

  unsigned short* Ktil = (unsigned short*)(ws);                   // 2 MB
  unsigned short* Qrow = (unsigned short*)(ws + (2u << 20));      // 2 MB
  unsigned short* Vtil = (unsigned short*)(ws + (4u << 20));      // 2 MB
  float* Opart = (float*)(ws + (6u << 20));

  int maxseg, segshift, sts, seg_tiles;
  if (ws_size >= ((size_t)24 << 20)) { maxseg = 4; segshift = 2; sts = 5; seg_tiles = 32; }
  else                               { maxseg = 1; segshift = 0; sts = 7; seg_tiles = 128; }
  float* MLpart = (float*)(ws + (6u << 20) + (size_t)maxseg * 512 * 2048 * 4);

  hipLaunchKernelGGL(proj_kernel, dim3(512), dim3(128), 0, stream,
                     x, Wk, bk, Wv, bv, Ktil, Qrow, Vtil);
  hipLaunchKernelGGL(attn_kernel, dim3(4 * 128 * maxseg), dim3(64), 0, stream,
                     Ktil, Qrow, Vtil, Opart, MLpart, seg_tiles, maxseg, segshift);
  hipLaunchKernelGGL(combine_kernel, dim3(512), dim3(256), 0, stream,
                     Opart, MLpart, out, sts, maxseg);
}